// Round 1
// baseline (458.486 us; speedup 1.0000x reference)
//
#include <hip/hip_runtime.h>

// TopologyNetwork: B=1024 batch, N=5000 nodes/level, K=16 fan-in, 9 levels.
// Strategy: keep activations in [N, B] layout in workspace (ping-pong), so a
// gather of node s for all batch elements is a contiguous 4KB row. One block
// per node, 256 threads x float4 covers B=1024 exactly.

#define TB 1024   // batch
#define TN 5000   // nodes per level
#define TK 16     // fan-in
#define TLV 9     // number of levels (L-1)

// ---- transpose x [B,N] -> act0 [N,B] ----
__global__ __launch_bounds__(256) void k_transpose_in(
    const float* __restrict__ x, float* __restrict__ out)
{
    __shared__ float tile[32][33];
    const int bx = blockIdx.x * 32;  // n tile origin
    const int by = blockIdx.y * 32;  // b tile origin
    const int tx = threadIdx.x;      // 0..31
    const int ty = threadIdx.y;      // 0..7
    #pragma unroll
    for (int j = 0; j < 32; j += 8) {
        int b = by + ty + j;
        int n = bx + tx;
        float v = 0.0f;
        if (n < TN) v = x[(size_t)b * TN + n];   // b always < TB (grid exact)
        tile[ty + j][tx] = v;
    }
    __syncthreads();
    #pragma unroll
    for (int j = 0; j < 32; j += 8) {
        int n = bx + ty + j;
        int b = by + tx;
        if (n < TN) out[(size_t)n * TB + b] = tile[tx][ty + j];
    }
}

// ---- one DAG level: out[n,b] = leaky(sum_k w[n,k]*in[src[n,k],b] + bias[n]) ----
__global__ __launch_bounds__(256) void k_level(
    const float* __restrict__ in,     // [N,B]
    float* __restrict__ out,          // [N,B]
    const int* __restrict__ idx,      // [N,K] this level
    const float* __restrict__ w,      // [N,K] this level
    const float* __restrict__ bias)   // [N]   this level
{
    const int n = blockIdx.x;
    const int t = threadIdx.x;
    const int base = t * 4;

    const int*   idx_r = idx + n * TK;
    const float* w_r   = w   + n * TK;

    const float bv = bias[n];
    float ax = bv, ay = bv, az = bv, aw = bv;

    #pragma unroll
    for (int k = 0; k < TK; ++k) {
        const int   s  = idx_r[k];   // block-uniform -> scalar load
        const float wk = w_r[k];     // block-uniform -> scalar load
        const float4 v = *reinterpret_cast<const float4*>(
            in + (size_t)s * TB + base);
        ax += wk * v.x;
        ay += wk * v.y;
        az += wk * v.z;
        aw += wk * v.w;
    }

    // LeakyReLU(0.1)
    ax = ax > 0.0f ? ax : 0.1f * ax;
    ay = ay > 0.0f ? ay : 0.1f * ay;
    az = az > 0.0f ? az : 0.1f * az;
    aw = aw > 0.0f ? aw : 0.1f * aw;

    float4 r = make_float4(ax, ay, az, aw);
    *reinterpret_cast<float4*>(out + (size_t)n * TB + base) = r;
}

// ---- transpose act [N,B] -> out [B,N] ----
__global__ __launch_bounds__(256) void k_transpose_out(
    const float* __restrict__ in, float* __restrict__ out)
{
    __shared__ float tile[32][33];
    const int bx = blockIdx.x * 32;  // b tile origin
    const int by = blockIdx.y * 32;  // n tile origin
    const int tx = threadIdx.x;
    const int ty = threadIdx.y;
    #pragma unroll
    for (int j = 0; j < 32; j += 8) {
        int n = by + ty + j;
        int b = bx + tx;
        float v = 0.0f;
        if (n < TN) v = in[(size_t)n * TB + b];
        tile[ty + j][tx] = v;
    }
    __syncthreads();
    #pragma unroll
    for (int j = 0; j < 32; j += 8) {
        int b = bx + ty + j;
        int n = by + tx;
        if (n < TN) out[(size_t)b * TN + n] = tile[tx][ty + j];
    }
}

extern "C" void kernel_launch(void* const* d_in, const int* in_sizes, int n_in,
                              void* d_out, int out_size, void* d_ws, size_t ws_size,
                              hipStream_t stream)
{
    const float* x       = (const float*)d_in[0];   // [B,N]
    const int*   src_idx = (const int*)  d_in[1];   // [LV,N,K]
    const float* weights = (const float*)d_in[2];   // [LV,N,K]
    const float* biases  = (const float*)d_in[3];   // [LV,N]
    float* out = (float*)d_out;                     // [B,N]

    float* bufA = (float*)d_ws;                     // [N,B]
    float* bufB = bufA + (size_t)TN * TB;           // [N,B]

    // x -> bufA in [N,B] layout
    {
        dim3 grid((TN + 31) / 32, TB / 32);
        dim3 blk(32, 8);
        hipLaunchKernelGGL(k_transpose_in, grid, blk, 0, stream, x, bufA);
    }

    float* cur = bufA;
    float* nxt = bufB;
    for (int l = 0; l < TLV; ++l) {
        hipLaunchKernelGGL(k_level, dim3(TN), dim3(256), 0, stream,
                           cur, nxt,
                           src_idx + (size_t)l * TN * TK,
                           weights + (size_t)l * TN * TK,
                           biases  + (size_t)l * TN);
        float* tmp = cur; cur = nxt; nxt = tmp;
    }

    // cur [N,B] -> out [B,N]
    {
        dim3 grid(TB / 32, (TN + 31) / 32);
        dim3 blk(32, 8);
        hipLaunchKernelGGL(k_transpose_out, grid, blk, 0, stream, cur, out);
    }
}

// Round 3
// 298.075 us; speedup vs baseline: 1.5382x; 1.5382x over previous
//
#include <hip/hip_runtime.h>

// TopologyNetwork: B=1024 batch, N=5000 nodes/level, K=16 fan-in, 9 levels.
// Activations live in [N, B] layout (ping-pong in d_ws) so a gather of node s
// is a contiguous row. R2: partition batch into 8 chunks of 128 columns and
// pin chunk -> XCD via blockIdx%8 round-robin, so each XCD's gather working
// set is 5000*128*4B = 2.56 MB < 4 MiB L2 (was 20.5 MB shared -> 60% hit).
// One node per wave (64 lanes x float2 = 128 cols); scalar idx/w/bias loads.
// R3: fix nontemporal store via ext_vector_type (HIP_vector_type rejected).

#define TB 1024   // batch
#define TN 5000   // nodes per level
#define TK 16     // fan-in
#define TLV 9     // number of levels (L-1)
#define CHUNK 128 // batch columns per XCD chunk
#define NCHUNK 8  // B / CHUNK == number of XCDs
#define WPB 4     // waves (=nodes) per block

typedef float vf2 __attribute__((ext_vector_type(2)));

// ---- transpose x [B,N] -> act0 [N,B] ----
__global__ __launch_bounds__(256) void k_transpose_in(
    const float* __restrict__ x, float* __restrict__ out)
{
    __shared__ float tile[32][33];
    const int bx = blockIdx.x * 32;  // n tile origin
    const int by = blockIdx.y * 32;  // b tile origin
    const int tx = threadIdx.x;      // 0..31
    const int ty = threadIdx.y;      // 0..7
    #pragma unroll
    for (int j = 0; j < 32; j += 8) {
        int b = by + ty + j;
        int n = bx + tx;
        float v = 0.0f;
        if (n < TN) v = x[(size_t)b * TN + n];
        tile[ty + j][tx] = v;
    }
    __syncthreads();
    #pragma unroll
    for (int j = 0; j < 32; j += 8) {
        int n = bx + ty + j;
        int b = by + tx;
        if (n < TN) out[(size_t)n * TB + b] = tile[tx][ty + j];
    }
}

// ---- one DAG level, XCD-chunked ----
// out[n, chunk-cols] = leaky(sum_k w[n,k] * in[src[n,k], chunk-cols] + bias[n])
__global__ __launch_bounds__(256) void k_level(
    const float* __restrict__ in,     // [N,B]
    float* __restrict__ out,          // [N,B]
    const int* __restrict__ idx,      // [N,K] this level
    const float* __restrict__ w,      // [N,K] this level
    const float* __restrict__ bias)   // [N]   this level
{
    const int chunk = blockIdx.x & (NCHUNK - 1);   // -> XCD id (round-robin)
    const int group = blockIdx.x >> 3;             // node group
    const int wave  = threadIdx.x >> 6;
    const int lane  = threadIdx.x & 63;

    // wave-uniform node id; force scalar so idx/w/bias go through s_load
    const int n = __builtin_amdgcn_readfirstlane(group * WPB + wave);
    const int col = chunk * CHUNK + lane * 2;

    const int*   idx_r = idx + n * TK;
    const float* w_r   = w   + n * TK;

    const float bv = bias[n];
    float ax = bv, ay = bv;

    #pragma unroll
    for (int k = 0; k < TK; ++k) {
        const int   s  = idx_r[k];
        const float wk = w_r[k];
        const vf2 v = *reinterpret_cast<const vf2*>(
            in + (size_t)s * TB + col);
        ax += wk * v.x;
        ay += wk * v.y;
    }

    ax = ax > 0.0f ? ax : 0.1f * ax;
    ay = ay > 0.0f ? ay : 0.1f * ay;

    vf2 r;
    r.x = ax;
    r.y = ay;
    // nontemporal: don't let the streaming output evict the gather slice in L2
    __builtin_nontemporal_store(r, reinterpret_cast<vf2*>(
        out + (size_t)n * TB + col));
}

// ---- transpose act [N,B] -> out [B,N] ----
__global__ __launch_bounds__(256) void k_transpose_out(
    const float* __restrict__ in, float* __restrict__ out)
{
    __shared__ float tile[32][33];
    const int bx = blockIdx.x * 32;  // b tile origin
    const int by = blockIdx.y * 32;  // n tile origin
    const int tx = threadIdx.x;
    const int ty = threadIdx.y;
    #pragma unroll
    for (int j = 0; j < 32; j += 8) {
        int n = by + ty + j;
        int b = bx + tx;
        float v = 0.0f;
        if (n < TN) v = in[(size_t)n * TB + b];
        tile[ty + j][tx] = v;
    }
    __syncthreads();
    #pragma unroll
    for (int j = 0; j < 32; j += 8) {
        int b = bx + ty + j;
        int n = by + tx;
        if (n < TN) out[(size_t)b * TN + n] = tile[tx][ty + j];
    }
}

extern "C" void kernel_launch(void* const* d_in, const int* in_sizes, int n_in,
                              void* d_out, int out_size, void* d_ws, size_t ws_size,
                              hipStream_t stream)
{
    const float* x       = (const float*)d_in[0];   // [B,N]
    const int*   src_idx = (const int*)  d_in[1];   // [LV,N,K]
    const float* weights = (const float*)d_in[2];   // [LV,N,K]
    const float* biases  = (const float*)d_in[3];   // [LV,N]
    float* out = (float*)d_out;                     // [B,N]

    float* bufA = (float*)d_ws;                     // [N,B]
    float* bufB = bufA + (size_t)TN * TB;           // [N,B]

    // x -> bufA in [N,B] layout
    {
        dim3 grid((TN + 31) / 32, TB / 32);
        dim3 blk(32, 8);
        hipLaunchKernelGGL(k_transpose_in, grid, blk, 0, stream, x, bufA);
    }

    float* cur = bufA;
    float* nxt = bufB;
    const int grid_level = NCHUNK * (TN / WPB);     // 8 * 1250 = 10000
    for (int l = 0; l < TLV; ++l) {
        hipLaunchKernelGGL(k_level, dim3(grid_level), dim3(256), 0, stream,
                           cur, nxt,
                           src_idx + (size_t)l * TN * TK,
                           weights + (size_t)l * TN * TK,
                           biases  + (size_t)l * TN);
        float* tmp = cur; cur = nxt; nxt = tmp;
    }

    // cur [N,B] -> out [B,N]
    {
        dim3 grid(TB / 32, (TN + 31) / 32);
        dim3 blk(32, 8);
        hipLaunchKernelGGL(k_transpose_out, grid, blk, 0, stream, cur, out);
    }
}

// Round 4
// 179.333 us; speedup vs baseline: 2.5566x; 1.6621x over previous
//
#include <hip/hip_runtime.h>

// TopologyNetwork: B=1024, N=5000, K=16, 9 levels.
// Activations in [N,B] layout, ping-pong in d_ws, stored as BF16 so both
// per-XCD slices (2 x 1.28 MB) fit the 4 MiB per-XCD L2. Batch split into 8
// chunks of 128 cols pinned to XCDs via blockIdx%8. Compute in fp32.
// One node per wave: 64 lanes x 2 bf16 cols (1 dword load) = 128 cols.

#define TB 1024   // batch
#define TN 5000   // nodes per level
#define TK 16     // fan-in
#define TLV 9     // number of levels (L-1)
#define CHUNK 128 // batch columns per XCD chunk
#define NCHUNK 8  // B / CHUNK == number of XCDs
#define WPB 4     // waves (=nodes) per block

__device__ __forceinline__ unsigned short f2bf(float f) {
    unsigned u = __float_as_uint(f);
    unsigned r = (u + 0x7fffu + ((u >> 16) & 1u)) >> 16;   // RNE
    return (unsigned short)r;
}
__device__ __forceinline__ float bflo(unsigned v) {        // low bf16 -> f32
    return __uint_as_float(v << 16);
}
__device__ __forceinline__ float bfhi(unsigned v) {        // high bf16 -> f32
    return __uint_as_float(v & 0xffff0000u);
}

// ---- transpose x f32 [B,N] -> act0 bf16 [N,B] ----
__global__ __launch_bounds__(256) void k_transpose_in(
    const float* __restrict__ x, unsigned short* __restrict__ out)
{
    __shared__ float tile[32][33];
    const int bx = blockIdx.x * 32;  // n tile origin
    const int by = blockIdx.y * 32;  // b tile origin
    const int tx = threadIdx.x;      // 0..31
    const int ty = threadIdx.y;      // 0..7
    #pragma unroll
    for (int j = 0; j < 32; j += 8) {
        int b = by + ty + j;
        int n = bx + tx;
        float v = 0.0f;
        if (n < TN) v = x[(size_t)b * TN + n];
        tile[ty + j][tx] = v;
    }
    __syncthreads();
    #pragma unroll
    for (int j = 0; j < 32; j += 8) {
        int n = bx + ty + j;
        int b = by + tx;
        if (n < TN) out[(size_t)n * TB + b] = f2bf(tile[tx][ty + j]);
    }
}

// ---- one DAG level, XCD-chunked, bf16 activations ----
__global__ __launch_bounds__(256) void k_level(
    const unsigned short* __restrict__ in,   // [N,B] bf16
    unsigned short* __restrict__ out,        // [N,B] bf16
    const int* __restrict__ idx,             // [N,K] this level
    const float* __restrict__ w,             // [N,K] this level
    const float* __restrict__ bias)          // [N]   this level
{
    const int chunk = blockIdx.x & (NCHUNK - 1);   // -> XCD id (round-robin)
    const int group = blockIdx.x >> 3;             // node group
    const int wave  = threadIdx.x >> 6;
    const int lane  = threadIdx.x & 63;

    // wave-uniform node id; scalar idx/w/bias loads
    const int n = __builtin_amdgcn_readfirstlane(group * WPB + wave);
    const int col = chunk * CHUNK + lane * 2;

    const int*   idx_r = idx + n * TK;
    const float* w_r   = w   + n * TK;

    const float bv = bias[n];
    float ax = bv, ay = bv;

    #pragma unroll
    for (int k = 0; k < TK; ++k) {
        const int   s  = idx_r[k];
        const float wk = w_r[k];
        const unsigned v = *reinterpret_cast<const unsigned*>(
            in + (size_t)s * TB + col);
        ax += wk * bflo(v);   // col   (low 2 bytes)
        ay += wk * bfhi(v);   // col+1 (high 2 bytes)
    }

    ax = ax > 0.0f ? ax : 0.1f * ax;
    ay = ay > 0.0f ? ay : 0.1f * ay;

    const unsigned packed = (unsigned)f2bf(ax) | ((unsigned)f2bf(ay) << 16);
    // normal (cached) store: next level gathers this slice from L2
    *reinterpret_cast<unsigned*>(out + (size_t)n * TB + col) = packed;
}

// ---- transpose act bf16 [N,B] -> out f32 [B,N] ----
__global__ __launch_bounds__(256) void k_transpose_out(
    const unsigned short* __restrict__ in, float* __restrict__ out)
{
    __shared__ float tile[32][33];
    const int bx = blockIdx.x * 32;  // b tile origin
    const int by = blockIdx.y * 32;  // n tile origin
    const int tx = threadIdx.x;
    const int ty = threadIdx.y;
    #pragma unroll
    for (int j = 0; j < 32; j += 8) {
        int n = by + ty + j;
        int b = bx + tx;
        float v = 0.0f;
        if (n < TN) v = bflo((unsigned)in[(size_t)n * TB + b]);
        tile[ty + j][tx] = v;
    }
    __syncthreads();
    #pragma unroll
    for (int j = 0; j < 32; j += 8) {
        int b = bx + ty + j;
        int n = by + tx;
        if (n < TN) out[(size_t)b * TN + n] = tile[tx][ty + j];
    }
}

extern "C" void kernel_launch(void* const* d_in, const int* in_sizes, int n_in,
                              void* d_out, int out_size, void* d_ws, size_t ws_size,
                              hipStream_t stream)
{
    const float* x       = (const float*)d_in[0];   // [B,N]
    const int*   src_idx = (const int*)  d_in[1];   // [LV,N,K]
    const float* weights = (const float*)d_in[2];   // [LV,N,K]
    const float* biases  = (const float*)d_in[3];   // [LV,N]
    float* out = (float*)d_out;                     // [B,N]

    unsigned short* bufA = (unsigned short*)d_ws;       // [N,B] bf16
    unsigned short* bufB = bufA + (size_t)TN * TB;      // [N,B] bf16

    // x -> bufA in [N,B] bf16 layout
    {
        dim3 grid((TN + 31) / 32, TB / 32);
        dim3 blk(32, 8);
        hipLaunchKernelGGL(k_transpose_in, grid, blk, 0, stream, x, bufA);
    }

    unsigned short* cur = bufA;
    unsigned short* nxt = bufB;
    const int grid_level = NCHUNK * (TN / WPB);     // 8 * 1250 = 10000
    for (int l = 0; l < TLV; ++l) {
        hipLaunchKernelGGL(k_level, dim3(grid_level), dim3(256), 0, stream,
                           cur, nxt,
                           src_idx + (size_t)l * TN * TK,
                           weights + (size_t)l * TN * TK,
                           biases  + (size_t)l * TN);
        unsigned short* tmp = cur; cur = nxt; nxt = tmp;
    }

    // cur bf16 [N,B] -> out f32 [B,N]
    {
        dim3 grid(TB / 32, (TN + 31) / 32);
        dim3 blk(32, 8);
        hipLaunchKernelGGL(k_transpose_out, grid, blk, 0, stream, cur, out);
    }
}